// Round 9
// baseline (310.434 us; speedup 1.0000x reference)
//
#include <hip/hip_runtime.h>

typedef float v4f __attribute__((ext_vector_type(4)));

namespace {
constexpr int B_     = 8;
constexpr int NT_    = 256;
constexpr int NX_    = 256;
constexpr int NREC_  = 64;
constexpr int PIECES = 32;             // 256 blocks -> all 256 CUs
constexpr int IROWS  = 8;              // interior rows per strip
constexpr int G      = 16;             // ghost width = steps per round
constexpr int ROUNDS = NT_ / G;        // 16 (15 exchanges)
constexpr int NBANDS = 5;              // R16: 5 waves x 8 rows (was 10 x 4)
constexpr int NTHR   = NBANDS * 64;    // 320 threads
constexpr int NBLK   = B_ * PIECES;    // 256 blocks
constexpr float DT2  = 1e-6f;          // DT*DT
constexpr float KLAP = 1e-8f;          // DT*DT/(DH*DH)
constexpr size_t FLAGS_BYTES = 4096;
constexpr int RCAP = 6;
} // namespace

// lane i <- lane i-1 (shfl_up 1). Lane 0 gets 0.0f (bound_ctrl) -- masked by cf=0.
__device__ __forceinline__ float dpp_shr1(float v) {
    return __int_as_float(__builtin_amdgcn_update_dpp(
        0, __float_as_int(v), 0x138 /*WAVE_SHR1*/, 0xF, 0xF, true));
}
// lane i <- lane i+1 (shfl_down 1). Lane 63 gets 0.0f -- masked by cf=0.
__device__ __forceinline__ float dpp_shl1(float v) {
    return __int_as_float(__builtin_amdgcn_update_dpp(
        0, __float_as_int(v), 0x130 /*WAVE_SHL1*/, 0xF, 0xF, true));
}

// R10: fence-free exchange via sc0 sc1 (system-coherent; bypasses the
// non-coherent per-XCD L2s). R13: trapezoid cutoffs (bit-identical).
// R15 decomposition: wall = VALU(rows/CU) + residue(DS pipe + per-wave
// overhead + barrier latency); residue scales with WAVE COUNT not rows.
// R16: 8-ROW BANDS -- a wave still publishes/reads only 2 boundary rows/step,
// so DS ops per CU-step halve and per-wave overhead amortizes over 2x rows.
// Trapezoid cuts for 5 bands: {7,15,16,15,7} (same frontier proof: publish
// window cut+1 covers the last consumer; wrongness propagates 1 row/step and
// only ever lands on dead rows -> bit-identical). Two-hop refill aligns 1:1:
// band0<-blk-2, band1<-blk-1, band3<-blk+1, band4<-blk+2, slab rows 0..7.
__device__ __forceinline__ void store_v4_sys(float* p, v4f v) {
    asm volatile("global_store_dwordx4 %0, %1, off sc0 sc1"
                 :: "v"(p), "v"(v) : "memory");
}
__device__ __forceinline__ v4f load_v4_sys(const float* p) {
    v4f r;
    asm volatile("global_load_dwordx4 %0, %1, off sc0 sc1"
                 : "=v"(r) : "v"(p) : "memory");
    return r;
}

extern "C" __global__
__attribute__((amdgpu_flat_work_group_size(NTHR, NTHR), amdgpu_waves_per_eu(2, 4)))
void wave_reg_kernel(const float* __restrict__ x,
                     const float* __restrict__ vp,
                     const int* __restrict__ src_loc,
                     const int* __restrict__ rec_loc,
                     float* __restrict__ out,
                     int* __restrict__ flags,   // [256] monotone round counters
                     float* __restrict__ gbuf)  // [par2][256][lvl2][8][256]
{
    __shared__ float pub[2][2][NBANDS][256];  // 20 KB: [par][top/bot][band][col]
    __shared__ float wav[NT_];                // 1 KB wavelet
    __shared__ float recbuf[G][NREC_];        // 4 KB receiver staging
    __shared__ unsigned char recown[NREC_];   // per-rec ownership of this block

    const int bid  = blockIdx.x;
    const int b    = bid & 7;
    const int p    = bid >> 3;             // 0..31
    const int blk  = b * PIECES + p;
    const int tid  = threadIdx.x;
    const int band = tid >> 6;             // wave id 0..4 -> 8 ext rows
    const int lane = tid & 63;
    const int c0   = lane << 2;            // first owned col (0..252)
    const int grt  = p * IROWS - G + (band << 3);  // global row of owned row 0

    // trapezoid cutoff: compute in-round step k (1-based) iff k<=cut;
    // publish iff k<=cut+1. cuts {7,15,16,15,7}.
    const int cut = (band < 2) ? ((band << 3) + 7)
                  : ((band == 2) ? 16 : (((4 - band) << 3) + 7));

    if (tid < NT_) wav[tid] = x[b * NT_ + tid];
    if (tid < NREC_) {
        int rz = rec_loc[(b * NREC_ + tid) * 2 + 0];
        recown[tid] = (rz >= p * IROWS && rz < p * IROWS + IROWS) ? 1 : 0;
    }

    // cf = vp^2*DT^2/DH^2, zeroed at Dirichlet boundary + out-of-domain rows.
    // cf2 = 2 - 4*cf: hn = cf*((N+S)+(E+W)) + (cf2*C - P)
    v4f cf[8], cf2[8];
#pragma unroll
    for (int i = 0; i < 8; ++i) {
        int gr = grt + i;
        int crow = gr < 0 ? 0 : (gr > 255 ? 255 : gr);
        bool rowok = (gr >= 1) && (gr <= 254);
        v4f vv = *(const v4f*)&vp[crow * NX_ + c0];
        float cc[4];
#pragma unroll
        for (int k = 0; k < 4; ++k) {
            int col = c0 + k;
            float vk = (k == 0) ? vv.x : (k == 1) ? vv.y : (k == 2) ? vv.z : vv.w;
            cc[k] = (rowok && col >= 1 && col <= 254) ? vk * vk * KLAP : 0.f;
        }
        cf[i].x = cc[0]; cf[i].y = cc[1]; cf[i].z = cc[2]; cf[i].w = cc[3];
        cf2[i].x = 2.f - 4.f * cc[0]; cf2[i].y = 2.f - 4.f * cc[1];
        cf2[i].z = 2.f - 4.f * cc[2]; cf2[i].w = 2.f - 4.f * cc[3];
    }

    // source ownership (ghost rows included: ghost evolution must replay it)
    const int sz = src_loc[b * 2 + 0], sx = src_loc[b * 2 + 1];
    const int si = sz - grt;               // 0..7 if owned row
    const int sj = sx - c0;                // 0..3 if owned col
    const bool has_src = ((unsigned)si < 8u) && ((unsigned)sj < 4u);
    const bool wave_has_src = __any(has_src);

    // receiver slots: interior owner only (unique writer). pk=(r<<5)|(i<<2)|j
    int rs[RCAP]; int rcnt = 0;
#pragma unroll 1
    for (int r = 0; r < NREC_; ++r) {
        int rz = rec_loc[(b * NREC_ + r) * 2 + 0];
        int rx = rec_loc[(b * NREC_ + r) * 2 + 1];
        int i = rz - grt, j = rx - c0;
        if (rz >= p * IROWS && rz < p * IROWS + IROWS &&
            (unsigned)i < 8u && (unsigned)j < 4u) {
            if (rcnt < RCAP) rs[rcnt] = (r << 5) | (i << 2) | j;
            ++rcnt;
        }
    }
    if (rcnt > RCAP) rcnt = RCAP;
    const bool wave_has_rec = __any(rcnt > 0);
    float* outb = out + (size_t)b * NT_ * NREC_;

    v4f A[8], Bv[8];
    {
        v4f z = {0.f, 0.f, 0.f, 0.f};
#pragma unroll
        for (int i = 0; i < 8; ++i) { A[i] = z; Bv[i] = z; }
    }

    // gbuf slab pointer: [par][blk][lvl][row(0..7)][col]; interior = the slab.
    auto gptr = [&](int e, int bk, int lvl, int rr) -> float* {
        return gbuf + ((((size_t)(e & 1) * NBLK + bk) * 2 + lvl) * 8 + rr) * 256;
    };

// one stencil row: reads C[I] +/- 1 and old P[I]; writes P[I]. Literal I only.
#define ROW(I, NV, SV) do {                                                   \
    float wv = dpp_shr1(C[I].w);   /* col c0-1 (lane0 -> 0: cf=0 masks) */    \
    float ev = dpp_shl1(C[I].x);   /* col c0+4 (lane63 -> 0: cf=0 masks) */   \
    v4f hn;                                                                   \
    { float sm = ((NV).x + (SV).x) + (wv     + C[I].y);                       \
      hn.x = fmaf(cf[I].x, sm, fmaf(cf2[I].x, C[I].x, -P[I].x)); }            \
    { float sm = ((NV).y + (SV).y) + (C[I].x + C[I].z);                       \
      hn.y = fmaf(cf[I].y, sm, fmaf(cf2[I].y, C[I].y, -P[I].y)); }            \
    { float sm = ((NV).z + (SV).z) + (C[I].y + C[I].w);                       \
      hn.z = fmaf(cf[I].z, sm, fmaf(cf2[I].z, C[I].z, -P[I].z)); }            \
    { float sm = ((NV).w + (SV).w) + (C[I].z + ev);                           \
      hn.w = fmaf(cf[I].w, sm, fmaf(cf2[I].w, C[I].w, -P[I].w)); }            \
    P[I] = hn;                                                                \
} while (0)

    // one step: P <- update(C, P); P becomes current. par = t&1.
    auto step = [&](v4f (&C)[8], v4f (&P)[8], int t, int par) {
        const int k = (t & (G - 1)) + 1;
        if (k <= cut + 1) {                 // publish window = compute window +1
            *(v4f*)&pub[par][0][band][c0] = C[0];  // top row (S halo of band-1)
            *(v4f*)&pub[par][1][band][c0] = C[7];  // bottom row (N halo of band+1)
        }
        __syncthreads();
        if (k > cut) return;                // all this band's rows are dead now
        v4f nn, ss;
        if (band > 0)          nn = *(const v4f*)&pub[par][1][band - 1][c0];
        else                   { nn.x = 0.f; nn.y = 0.f; nn.z = 0.f; nn.w = 0.f; }
        if (band < NBANDS - 1) ss = *(const v4f*)&pub[par][0][band + 1][c0];
        else                   { ss.x = 0.f; ss.y = 0.f; ss.z = 0.f; ss.w = 0.f; }
        // inner rows first: their VALU hides the halo ds_read latency
        ROW(1, C[0], C[2]);
        ROW(2, C[1], C[3]);
        ROW(3, C[2], C[4]);
        ROW(4, C[3], C[5]);
        ROW(5, C[4], C[6]);
        ROW(6, C[5], C[7]);
        ROW(0, nn,   C[1]);
        ROW(7, C[6], ss);
        if (wave_has_src) {
            const float sv = DT2 * wav[t];
#pragma unroll
            for (int i = 0; i < 8; ++i) {
                if (has_src && si == i) {
                    if      (sj == 0) P[i].x += sv;
                    else if (sj == 1) P[i].y += sv;
                    else if (sj == 2) P[i].z += sv;
                    else              P[i].w += sv;
                }
            }
        }
        if (wave_has_rec) {
#pragma unroll
            for (int kk = 0; kk < RCAP; ++kk) {
                if (rcnt > kk) {
                    int pk = rs[kk];
                    int i = (pk >> 2) & 7, j = pk & 3, r = pk >> 5;
                    v4f lo = (i & 2) ? ((i & 1) ? P[3] : P[2])
                                     : ((i & 1) ? P[1] : P[0]);
                    v4f hi = (i & 2) ? ((i & 1) ? P[7] : P[6])
                                     : ((i & 1) ? P[5] : P[4]);
                    v4f rw = (i & 4) ? hi : lo;
                    float c01 = (j & 1) ? rw.y : rw.x;
                    float c23 = (j & 1) ? rw.w : rw.z;
                    recbuf[t & (G - 1)][r] = (j & 2) ? c23 : c01;
                }
            }
        }
        // no trailing barrier: next step uses pub[par^1] (parity double-buffer)
    };

    // early publish of prev level (Bv final before the round's last step):
    // store drain overlaps the final step. Interior band 2 only.
    auto publish_prev = [&](int e) {
        if (band == 2) {
#pragma unroll
            for (int i = 0; i < 8; ++i)
                store_v4_sys(&gptr(e, blk, 1, i)[c0], Bv[i]);
        }
    };

    // two-hop exchange after round e: publish interior (cur), drain via the
    // barrier's vmcnt(0), flag (fire-and-forget), ghost waves poll the flag of
    // THEIR source block (+-1 / +-2) and refill. Slab rows = 0..7 = i for all.
    auto exchange = [&](int e) {
        if (band == 2) {                   // publish interior, cur level
#pragma unroll
            for (int i = 0; i < 8; ++i)
                store_v4_sys(&gptr(e, blk, 0, i)[c0], A[i]);
        }
        __syncthreads();                   // drains each wave's vmcnt first
        if (tid == 0)                      // fire-and-forget; neighbors poll
            __hip_atomic_store(&flags[blk], e + 1, __ATOMIC_RELAXED,
                               __HIP_MEMORY_SCOPE_SYSTEM);
        // wave-level poll: lane0 loop holds the wave's PC; refill loads are
        // control-dependent on the flag trip.
        if (band == 0 && p >= 2) {         // ext rows 0..7  <- blk-2 interior
            if (lane == 0)
                while (__hip_atomic_load(&flags[blk - 2], __ATOMIC_RELAXED,
                                         __HIP_MEMORY_SCOPE_SYSTEM) < e + 1)
                    __builtin_amdgcn_s_sleep(1);
#pragma unroll
            for (int i = 0; i < 8; ++i) {
                A[i]  = load_v4_sys(&gptr(e, blk - 2, 0, i)[c0]);
                Bv[i] = load_v4_sys(&gptr(e, blk - 2, 1, i)[c0]);
            }
        }
        if (band == 1 && p >= 1) {         // ext rows 8..15 <- blk-1 interior
            if (lane == 0)
                while (__hip_atomic_load(&flags[blk - 1], __ATOMIC_RELAXED,
                                         __HIP_MEMORY_SCOPE_SYSTEM) < e + 1)
                    __builtin_amdgcn_s_sleep(1);
#pragma unroll
            for (int i = 0; i < 8; ++i) {
                A[i]  = load_v4_sys(&gptr(e, blk - 1, 0, i)[c0]);
                Bv[i] = load_v4_sys(&gptr(e, blk - 1, 1, i)[c0]);
            }
        }
        if (band == 3 && p < PIECES - 1) { // ext rows 24..31 <- blk+1 interior
            if (lane == 0)
                while (__hip_atomic_load(&flags[blk + 1], __ATOMIC_RELAXED,
                                         __HIP_MEMORY_SCOPE_SYSTEM) < e + 1)
                    __builtin_amdgcn_s_sleep(1);
#pragma unroll
            for (int i = 0; i < 8; ++i) {
                A[i]  = load_v4_sys(&gptr(e, blk + 1, 0, i)[c0]);
                Bv[i] = load_v4_sys(&gptr(e, blk + 1, 1, i)[c0]);
            }
        }
        if (band == 4 && p < PIECES - 2) { // ext rows 32..39 <- blk+2 interior
            if (lane == 0)
                while (__hip_atomic_load(&flags[blk + 2], __ATOMIC_RELAXED,
                                         __HIP_MEMORY_SCOPE_SYSTEM) < e + 1)
                    __builtin_amdgcn_s_sleep(1);
#pragma unroll
            for (int i = 0; i < 8; ++i) {
                A[i]  = load_v4_sys(&gptr(e, blk + 2, 0, i)[c0]);
                Bv[i] = load_v4_sys(&gptr(e, blk + 2, 1, i)[c0]);
            }
        }
        // asm loads are opaque to compiler waitcnt logic (rule #18)
        asm volatile("s_waitcnt vmcnt(0)" ::: "memory");
        __builtin_amdgcn_sched_barrier(0);
        __syncthreads();                   // all waves aligned for next round
    };

    int t = 0;
#pragma unroll 1
    for (int e = 0; e < ROUNDS; ++e) {
#pragma unroll 1
        for (int s = 0; s < G; s += 2) {
            step(A, Bv, t, 0);      // t even: cur=A, par=0
            if (s == G - 2 && e < ROUNDS - 1)
                publish_prev(e);    // Bv = lvl t_end-1 is final; overlap drain
            step(Bv, A, t + 1, 1);  // t odd:  cur=B, par=1
            t += 2;
        }
        // flush this round's receiver samples (G*NREC=1024 slots, 320 threads)
        __syncthreads();           // recbuf writes came from scattered owners
#pragma unroll 1
        for (int idx = tid; idx < G * NREC_; idx += NTHR) {
            int s = idx >> 6, r = idx & 63;
            if (recown[r]) outb[(e * G + s) * NREC_ + r] = recbuf[s][r];
        }
        if (e < ROUNDS - 1) exchange(e);
    }
#undef ROW
}

extern "C" void kernel_launch(void* const* d_in, const int* in_sizes, int n_in,
                              void* d_out, int out_size, void* d_ws, size_t ws_size,
                              hipStream_t stream) {
    const float* x   = (const float*)d_in[0];
    const float* vp  = (const float*)d_in[1];
    const int*   src = (const int*)d_in[2];
    const int*   rec = (const int*)d_in[3];
    float*       o   = (float*)d_out;
    int*   flags = (int*)d_ws;
    float* gbuf  = (float*)((char*)d_ws + FLAGS_BYTES);
    (void)hipMemsetAsync(d_ws, 0, FLAGS_BYTES, stream);   // flags must start at 0
    hipLaunchKernelGGL(wave_reg_kernel, dim3(NBLK), dim3(NTHR), 0, stream,
                       x, vp, src, rec, o, flags, gbuf);
}